// Round 1
// baseline (3589.009 us; speedup 1.0000x reference)
//
#include <hip/hip_runtime.h>

#define NUM_GRID_NODES 262144
#define NUM_MESH_NODES 40962
#define EMBED 64
#define NUM_EDGES 1048576
#define BATCH 4

// --- Kernel 1: histogram of dst -> counts ---
__global__ void count_kernel(const int* __restrict__ edge_index,
                             int* __restrict__ counts) {
    int e = blockIdx.x * blockDim.x + threadIdx.x;
    if (e < NUM_EDGES) {
        int dst = edge_index[2 * e + 1];
        atomicAdd(&counts[dst], 1);
    }
}

// --- Kernel 2: scatter-add gathered features ---
// 16 lanes per edge, each lane handles 4 consecutive floats (float4),
// loops over the 4 batches.
__global__ void scatter_kernel(const float* __restrict__ grid,
                               const int* __restrict__ edge_index,
                               float* __restrict__ out) {
    unsigned t = blockIdx.x * blockDim.x + threadIdx.x;
    unsigned e = t >> 4;      // edge id
    unsigned lane = t & 15;   // 16 lanes x float4 = 64 floats
    if (e >= NUM_EDGES) return;
    int src = edge_index[2 * e];
    int dst = edge_index[2 * e + 1];
    unsigned off = lane * 4;
#pragma unroll
    for (int b = 0; b < BATCH; ++b) {
        const float4 v = *reinterpret_cast<const float4*>(
            &grid[((size_t)b * NUM_GRID_NODES + (size_t)src) * EMBED + off]);
        float* o = &out[((size_t)b * NUM_MESH_NODES + (size_t)dst) * EMBED + off];
        atomicAdd(o + 0, v.x);
        atomicAdd(o + 1, v.y);
        atomicAdd(o + 2, v.z);
        atomicAdd(o + 3, v.w);
    }
}

// --- Kernel 3: divide by max(count, 1), vectorized float4 ---
__global__ void divide_kernel(float* __restrict__ out,
                              const int* __restrict__ counts) {
    size_t i = ((size_t)blockIdx.x * blockDim.x + threadIdx.x) * 4;
    const size_t total = (size_t)BATCH * NUM_MESH_NODES * EMBED;
    if (i >= total) return;
    int node = (int)((i >> 6) % NUM_MESH_NODES);
    float inv = 1.0f / fmaxf((float)counts[node], 1.0f);
    float4 v = *reinterpret_cast<float4*>(&out[i]);
    v.x *= inv; v.y *= inv; v.z *= inv; v.w *= inv;
    *reinterpret_cast<float4*>(&out[i]) = v;
}

extern "C" void kernel_launch(void* const* d_in, const int* in_sizes, int n_in,
                              void* d_out, int out_size, void* d_ws, size_t ws_size,
                              hipStream_t stream) {
    const float* grid = (const float*)d_in[0];
    const int* edge_index = (const int*)d_in[1];
    float* out = (float*)d_out;
    int* counts = (int*)d_ws;

    // zero accumulators (d_out / d_ws are poisoned, not zeroed, by harness)
    hipMemsetAsync(d_out, 0, (size_t)out_size * sizeof(float), stream);
    hipMemsetAsync(counts, 0, (size_t)NUM_MESH_NODES * sizeof(int), stream);

    count_kernel<<<(NUM_EDGES + 255) / 256, 256, 0, stream>>>(edge_index, counts);

    const unsigned scatter_threads = NUM_EDGES * 16u;
    scatter_kernel<<<scatter_threads / 256, 256, 0, stream>>>(grid, edge_index, out);

    const size_t total = (size_t)BATCH * NUM_MESH_NODES * EMBED;
    divide_kernel<<<(unsigned)((total / 4 + 255) / 256), 256, 0, stream>>>(out, counts);
}

// Round 2
// 370.292 us; speedup vs baseline: 9.6924x; 9.6924x over previous
//
#include <hip/hip_runtime.h>

#define NUM_GRID_NODES 262144
#define NUM_MESH_NODES 40962
#define EMBED 64
#define NUM_EDGES 1048576
#define BATCH 4

// ws layout: cursor[NUM_MESH_NODES] | offsets[NUM_MESH_NODES+1] | sorted_src[NUM_EDGES]

// --- Kernel 1: histogram of dst into cursor ---
__global__ void count_kernel(const int* __restrict__ edge_index,
                             int* __restrict__ cursor) {
    int e = blockIdx.x * blockDim.x + threadIdx.x;
    if (e < NUM_EDGES) {
        int dst = edge_index[2 * e + 1];
        atomicAdd(&cursor[dst], 1);
    }
}

// --- Kernel 2: single-block exclusive scan; cursor (counts) -> offsets,
//     and rewrite cursor with the exclusive scan (running write positions) ---
__global__ void scan_kernel(int* __restrict__ cursor,
                            int* __restrict__ offsets) {
    __shared__ int tmp[1024];
    __shared__ int carry;
    if (threadIdx.x == 0) carry = 0;
    __syncthreads();
    for (int base = 0; base < NUM_MESH_NODES; base += 1024) {
        int i = base + (int)threadIdx.x;
        int v = (i < NUM_MESH_NODES) ? cursor[i] : 0;
        tmp[threadIdx.x] = v;
        __syncthreads();
        // inclusive scan over the 1024-chunk
        for (int s = 1; s < 1024; s <<= 1) {
            int t = (threadIdx.x >= (unsigned)s) ? tmp[threadIdx.x - s] : 0;
            __syncthreads();
            tmp[threadIdx.x] += t;
            __syncthreads();
        }
        int excl = tmp[threadIdx.x] - v;
        if (i < NUM_MESH_NODES) {
            int o = carry + excl;
            offsets[i] = o;
            cursor[i] = o;
        }
        __syncthreads();
        if (threadIdx.x == 1023) carry += tmp[1023];
        __syncthreads();
    }
    if (threadIdx.x == 0) offsets[NUM_MESH_NODES] = carry;
}

// --- Kernel 3: scatter src ids into dst-sorted order ---
__global__ void permute_kernel(const int* __restrict__ edge_index,
                               int* __restrict__ cursor,
                               int* __restrict__ sorted_src) {
    int e = blockIdx.x * blockDim.x + threadIdx.x;
    if (e < NUM_EDGES) {
        int2 sd = *reinterpret_cast<const int2*>(&edge_index[2 * e]);
        int pos = atomicAdd(&cursor[sd.y], 1);
        sorted_src[pos] = sd.x;
    }
}

// --- Kernel 4: one wave per mesh node; lane = embed element.
//     Gather-reduce the node's edge segment for all 4 batches, scale, store. ---
__global__ void aggregate_kernel(const float* __restrict__ grid,
                                 const int* __restrict__ sorted_src,
                                 const int* __restrict__ offsets,
                                 float* __restrict__ out) {
    const int node = blockIdx.x * 4 + ((int)threadIdx.x >> 6);
    const int lane = (int)threadIdx.x & 63;
    if (node >= NUM_MESH_NODES) return;
    const int beg = offsets[node];
    const int end = offsets[node + 1];

    const size_t GSTRIDE = (size_t)NUM_GRID_NODES * EMBED;  // batch stride in grid
    float acc0 = 0.f, acc1 = 0.f, acc2 = 0.f, acc3 = 0.f;
    for (int e = beg; e < end; ++e) {
        const int s = sorted_src[e];  // wave-uniform broadcast load
        const float* g = &grid[(size_t)s * EMBED + lane];
        acc0 += g[0];
        acc1 += g[GSTRIDE];
        acc2 += g[2 * GSTRIDE];
        acc3 += g[3 * GSTRIDE];
    }
    const float inv = 1.0f / fmaxf((float)(end - beg), 1.0f);
    const size_t OSTRIDE = (size_t)NUM_MESH_NODES * EMBED;  // batch stride in out
    float* o = &out[(size_t)node * EMBED + lane];
    o[0]           = acc0 * inv;
    o[OSTRIDE]     = acc1 * inv;
    o[2 * OSTRIDE] = acc2 * inv;
    o[3 * OSTRIDE] = acc3 * inv;
}

extern "C" void kernel_launch(void* const* d_in, const int* in_sizes, int n_in,
                              void* d_out, int out_size, void* d_ws, size_t ws_size,
                              hipStream_t stream) {
    const float* grid = (const float*)d_in[0];
    const int* edge_index = (const int*)d_in[1];
    float* out = (float*)d_out;

    int* cursor = (int*)d_ws;
    int* offsets = cursor + NUM_MESH_NODES;
    int* sorted_src = offsets + (NUM_MESH_NODES + 1);

    hipMemsetAsync(cursor, 0, (size_t)NUM_MESH_NODES * sizeof(int), stream);

    count_kernel<<<(NUM_EDGES + 255) / 256, 256, 0, stream>>>(edge_index, cursor);
    scan_kernel<<<1, 1024, 0, stream>>>(cursor, offsets);
    permute_kernel<<<(NUM_EDGES + 255) / 256, 256, 0, stream>>>(edge_index, cursor, sorted_src);

    const int blocks = (NUM_MESH_NODES + 3) / 4;  // 4 waves (nodes) per 256-thread block
    aggregate_kernel<<<blocks, 256, 0, stream>>>(grid, sorted_src, offsets, out);
}

// Round 3
// 355.588 us; speedup vs baseline: 10.0932x; 1.0413x over previous
//
#include <hip/hip_runtime.h>

#define NUM_GRID_NODES 262144
#define NUM_MESH_NODES 40962
#define EMBED 64
#define NUM_EDGES 1048576
#define BATCH 4

// ws layout: cursor[NUM_MESH_NODES] | offsets[NUM_MESH_NODES+1] | sorted_src[NUM_EDGES]

// --- Kernel 1: histogram of dst (2 edges per thread, int4 load) ---
__global__ void count_kernel(const int* __restrict__ edge_index,
                             int* __restrict__ cursor) {
    int t = blockIdx.x * blockDim.x + threadIdx.x;
    int e0 = t * 2;
    if (e0 < NUM_EDGES) {  // NUM_EDGES is even -> always a full pair
        int4 v = *reinterpret_cast<const int4*>(&edge_index[2 * e0]);
        atomicAdd(&cursor[v.y], 1);
        atomicAdd(&cursor[v.w], 1);
    }
}

// --- Kernel 2: single-block exclusive scan, thread-coarsened.
//     1024 threads x 41 nodes each; wave shuffle-scan + tiny LDS block scan. ---
__global__ __launch_bounds__(1024) void scan_kernel(int* __restrict__ cursor,
                                                    int* __restrict__ offsets) {
    const int ITEMS = (NUM_MESH_NODES + 1023) / 1024;  // 41
    const int tid = (int)threadIdx.x;
    const int beg = tid * ITEMS;
    const int end = min(beg + ITEMS, NUM_MESH_NODES);

    int local = 0;
    for (int i = beg; i < end; ++i) local += cursor[i];

    const int lane = tid & 63, wid = tid >> 6;
    int incl = local;
    for (int d = 1; d < 64; d <<= 1) {
        int v = __shfl_up(incl, d, 64);
        if (lane >= d) incl += v;
    }

    __shared__ int wsum[16];
    __shared__ int wpre[16];
    if (lane == 63) wsum[wid] = incl;
    __syncthreads();
    if (tid == 0) {
        int run = 0;
        for (int w = 0; w < 16; ++w) { wpre[w] = run; run += wsum[w]; }
        offsets[NUM_MESH_NODES] = run;  // == NUM_EDGES
    }
    __syncthreads();

    int run = wpre[wid] + (incl - local);  // exclusive prefix for this thread
    for (int i = beg; i < end; ++i) {
        int c = cursor[i];
        offsets[i] = run;
        cursor[i] = run;
        run += c;
    }
}

// --- Kernel 3: scatter src ids into dst-sorted order (2 edges per thread) ---
__global__ void permute_kernel(const int* __restrict__ edge_index,
                               int* __restrict__ cursor,
                               int* __restrict__ sorted_src) {
    int t = blockIdx.x * blockDim.x + threadIdx.x;
    int e0 = t * 2;
    if (e0 < NUM_EDGES) {
        int4 v = *reinterpret_cast<const int4*>(&edge_index[2 * e0]);
        int p0 = atomicAdd(&cursor[v.y], 1);
        sorted_src[p0] = v.x;
        int p1 = atomicAdd(&cursor[v.w], 1);
        sorted_src[p1] = v.z;
    }
}

// --- Kernel 4: one wave per mesh node, lane = embed element, unroll-4 over edges ---
__global__ void aggregate_kernel(const float* __restrict__ grid,
                                 const int* __restrict__ sorted_src,
                                 const int* __restrict__ offsets,
                                 float* __restrict__ out) {
    const int node = blockIdx.x * 4 + ((int)threadIdx.x >> 6);
    const int lane = (int)threadIdx.x & 63;
    if (node >= NUM_MESH_NODES) return;
    const int beg = offsets[node];
    const int end = offsets[node + 1];

    const size_t GS = (size_t)NUM_GRID_NODES * EMBED;  // batch stride in grid
    float a0 = 0.f, a1 = 0.f, a2 = 0.f, a3 = 0.f;

    int e = beg;
    for (; e + 4 <= end; e += 4) {
        // wave-uniform scalar loads of 4 src ids, then 16 independent vector loads
        const int s0 = sorted_src[e], s1 = sorted_src[e + 1];
        const int s2 = sorted_src[e + 2], s3 = sorted_src[e + 3];
        const float* g0 = &grid[(size_t)s0 * EMBED + lane];
        const float* g1 = &grid[(size_t)s1 * EMBED + lane];
        const float* g2 = &grid[(size_t)s2 * EMBED + lane];
        const float* g3 = &grid[(size_t)s3 * EMBED + lane];
        float v00 = g0[0], v01 = g0[GS], v02 = g0[2 * GS], v03 = g0[3 * GS];
        float v10 = g1[0], v11 = g1[GS], v12 = g1[2 * GS], v13 = g1[3 * GS];
        float v20 = g2[0], v21 = g2[GS], v22 = g2[2 * GS], v23 = g2[3 * GS];
        float v30 = g3[0], v31 = g3[GS], v32 = g3[2 * GS], v33 = g3[3 * GS];
        a0 += (v00 + v10) + (v20 + v30);
        a1 += (v01 + v11) + (v21 + v31);
        a2 += (v02 + v12) + (v22 + v32);
        a3 += (v03 + v13) + (v23 + v33);
    }
    for (; e < end; ++e) {
        const int s = sorted_src[e];
        const float* g = &grid[(size_t)s * EMBED + lane];
        a0 += g[0]; a1 += g[GS]; a2 += g[2 * GS]; a3 += g[3 * GS];
    }

    const float inv = 1.0f / fmaxf((float)(end - beg), 1.0f);
    const size_t OS = (size_t)NUM_MESH_NODES * EMBED;  // batch stride in out
    float* o = &out[(size_t)node * EMBED + lane];
    o[0]          = a0 * inv;
    o[OS]         = a1 * inv;
    o[2 * OS]     = a2 * inv;
    o[3 * OS]     = a3 * inv;
}

extern "C" void kernel_launch(void* const* d_in, const int* in_sizes, int n_in,
                              void* d_out, int out_size, void* d_ws, size_t ws_size,
                              hipStream_t stream) {
    const float* grid = (const float*)d_in[0];
    const int* edge_index = (const int*)d_in[1];
    float* out = (float*)d_out;

    int* cursor = (int*)d_ws;
    int* offsets = cursor + NUM_MESH_NODES;
    int* sorted_src = offsets + (NUM_MESH_NODES + 1);

    hipMemsetAsync(cursor, 0, (size_t)NUM_MESH_NODES * sizeof(int), stream);

    const int pair_blocks = (NUM_EDGES / 2 + 255) / 256;
    count_kernel<<<pair_blocks, 256, 0, stream>>>(edge_index, cursor);
    scan_kernel<<<1, 1024, 0, stream>>>(cursor, offsets);
    permute_kernel<<<pair_blocks, 256, 0, stream>>>(edge_index, cursor, sorted_src);

    const int blocks = (NUM_MESH_NODES + 3) / 4;  // 4 waves (nodes) per 256-thread block
    aggregate_kernel<<<blocks, 256, 0, stream>>>(grid, sorted_src, offsets, out);
}

// Round 4
// 331.988 us; speedup vs baseline: 10.8106x; 1.0711x over previous
//
#include <hip/hip_runtime.h>

#define NUM_GRID_NODES 262144
#define NUM_MESH_NODES 40962
#define EMBED 64
#define NUM_EDGES 1048576
#define BATCH 4

// ws layout: cursor[NUM_MESH_NODES] | offsets[NUM_MESH_NODES+1] | sorted_src[NUM_EDGES]

// --- Kernel 1: histogram of dst (4 edges per thread, 2x int4) ---
__global__ void count_kernel(const int* __restrict__ edge_index,
                             int* __restrict__ cursor) {
    int t = blockIdx.x * blockDim.x + threadIdx.x;
    int e0 = t * 4;
    if (e0 < NUM_EDGES) {  // NUM_EDGES % 4 == 0 -> always full quads
        int4 a = *reinterpret_cast<const int4*>(&edge_index[2 * e0]);
        int4 b = *reinterpret_cast<const int4*>(&edge_index[2 * e0 + 4]);
        atomicAdd(&cursor[a.y], 1);
        atomicAdd(&cursor[a.w], 1);
        atomicAdd(&cursor[b.y], 1);
        atomicAdd(&cursor[b.w], 1);
    }
}

// --- Kernel 2: single-block exclusive scan, thread-coarsened ---
__global__ __launch_bounds__(1024) void scan_kernel(int* __restrict__ cursor,
                                                    int* __restrict__ offsets) {
    const int ITEMS = (NUM_MESH_NODES + 1023) / 1024;  // 41
    const int tid = (int)threadIdx.x;
    const int beg = tid * ITEMS;
    const int end = min(beg + ITEMS, NUM_MESH_NODES);

    int local = 0;
    for (int i = beg; i < end; ++i) local += cursor[i];

    const int lane = tid & 63, wid = tid >> 6;
    int incl = local;
    for (int d = 1; d < 64; d <<= 1) {
        int v = __shfl_up(incl, d, 64);
        if (lane >= d) incl += v;
    }

    __shared__ int wsum[16];
    __shared__ int wpre[16];
    if (lane == 63) wsum[wid] = incl;
    __syncthreads();
    if (tid == 0) {
        int run = 0;
        for (int w = 0; w < 16; ++w) { wpre[w] = run; run += wsum[w]; }
        offsets[NUM_MESH_NODES] = run;  // == NUM_EDGES
    }
    __syncthreads();

    int run = wpre[wid] + (incl - local);  // exclusive prefix for this thread
    for (int i = beg; i < end; ++i) {
        int c = cursor[i];
        offsets[i] = run;
        cursor[i] = run;
        run += c;
    }
}

// --- Kernel 3: scatter src ids into dst-sorted order (4 edges per thread) ---
__global__ void permute_kernel(const int* __restrict__ edge_index,
                               int* __restrict__ cursor,
                               int* __restrict__ sorted_src) {
    int t = blockIdx.x * blockDim.x + threadIdx.x;
    int e0 = t * 4;
    if (e0 < NUM_EDGES) {
        int4 a = *reinterpret_cast<const int4*>(&edge_index[2 * e0]);
        int4 b = *reinterpret_cast<const int4*>(&edge_index[2 * e0 + 4]);
        sorted_src[atomicAdd(&cursor[a.y], 1)] = a.x;
        sorted_src[atomicAdd(&cursor[a.w], 1)] = a.z;
        sorted_src[atomicAdd(&cursor[b.y], 1)] = b.x;
        sorted_src[atomicAdd(&cursor[b.w], 1)] = b.z;
    }
}

// --- Kernel 4: wave = one (node, batch). Batch pinned to an XCD pair via
//     blockIdx%8 round-robin mapping: batch = (blockIdx%8)>>1, so each XCD's
//     L2 only sees ONE batch's 10.5 MB hot region (vs 42 MB for all 4). ---
__global__ void aggregate_kernel(const float* __restrict__ grid,
                                 const int* __restrict__ sorted_src,
                                 const int* __restrict__ offsets,
                                 float* __restrict__ out) {
    const int m = (int)blockIdx.x & 7;
    const int batch = m >> 1;                              // XCDs {2b, 2b+1}
    const int local = (((int)blockIdx.x >> 3) << 1) + (m & 1);
    const int node = local * 4 + ((int)threadIdx.x >> 6);  // 4 waves/block
    const int lane = (int)threadIdx.x & 63;
    if (node >= NUM_MESH_NODES) return;

    const int beg = offsets[node];
    const int end = offsets[node + 1];
    const float* gb = grid + (size_t)batch * NUM_GRID_NODES * EMBED + lane;

    float a0 = 0.f, a1 = 0.f, a2 = 0.f, a3 = 0.f;
    float a4 = 0.f, a5 = 0.f, a6 = 0.f, a7 = 0.f;
    int e = beg;
    for (; e + 8 <= end; e += 8) {
        int s0 = sorted_src[e + 0], s1 = sorted_src[e + 1];
        int s2 = sorted_src[e + 2], s3 = sorted_src[e + 3];
        int s4 = sorted_src[e + 4], s5 = sorted_src[e + 5];
        int s6 = sorted_src[e + 6], s7 = sorted_src[e + 7];
        a0 += gb[(size_t)s0 * EMBED];
        a1 += gb[(size_t)s1 * EMBED];
        a2 += gb[(size_t)s2 * EMBED];
        a3 += gb[(size_t)s3 * EMBED];
        a4 += gb[(size_t)s4 * EMBED];
        a5 += gb[(size_t)s5 * EMBED];
        a6 += gb[(size_t)s6 * EMBED];
        a7 += gb[(size_t)s7 * EMBED];
    }
    for (; e < end; ++e) {
        a0 += gb[(size_t)sorted_src[e] * EMBED];
    }
    float acc = ((a0 + a1) + (a2 + a3)) + ((a4 + a5) + (a6 + a7));

    const float inv = 1.0f / fmaxf((float)(end - beg), 1.0f);
    out[((size_t)batch * NUM_MESH_NODES + (size_t)node) * EMBED + lane] = acc * inv;
}

extern "C" void kernel_launch(void* const* d_in, const int* in_sizes, int n_in,
                              void* d_out, int out_size, void* d_ws, size_t ws_size,
                              hipStream_t stream) {
    const float* grid = (const float*)d_in[0];
    const int* edge_index = (const int*)d_in[1];
    float* out = (float*)d_out;

    int* cursor = (int*)d_ws;
    int* offsets = cursor + NUM_MESH_NODES;
    int* sorted_src = offsets + (NUM_MESH_NODES + 1);

    hipMemsetAsync(cursor, 0, (size_t)NUM_MESH_NODES * sizeof(int), stream);

    const int quad_blocks = (NUM_EDGES / 4 + 255) / 256;  // 1024 blocks
    count_kernel<<<quad_blocks, 256, 0, stream>>>(edge_index, cursor);
    scan_kernel<<<1, 1024, 0, stream>>>(cursor, offsets);
    permute_kernel<<<quad_blocks, 256, 0, stream>>>(edge_index, cursor, sorted_src);

    // grid must be divisible by 8; per-batch block supply = grid/4 >= ceil(40962/4)
    const int agg_grid = 40968;
    aggregate_kernel<<<agg_grid, 256, 0, stream>>>(grid, sorted_src, offsets, out);
}